// Round 2
// baseline (3128.614 us; speedup 1.0000x reference)
//
#include <hip/hip_runtime.h>
#include <stdint.h>
#include <math.h>

typedef unsigned int u32;
typedef unsigned long long u64;

#define Bb 4
#define Nn 8192
#define Dd 64
#define Kk 32
#define MAXIT 30
#define NBLK 256    // 4 batches x 64 chunks; 512 thr: 128 points x 4 k-groups
#define NTHR 512
#define PPB  128

// ---- workspace layout (bytes); total ~4.76 MB ----
enum : u32 {
  WS_BAR   = 0u,
  WS_SEL   = 64u,
  WS_MASKH = 192u,      // [par][128] u32 full masks of head points
  WS_C0    = 1280u,     // 4*32*64 f
  WS_XHEAD = 34048u,    // 4*32*64 f
  WS_KEYS1 = 66816u,
  WS_KEYS2 = 99584u,
  WS_A1K   = 132352u,
  WS_A1V   = 165120u,
  WS_A2K   = 197888u,
  WS_A2V   = 230656u,
  WS_PCHG  = 263424u,   // [par][256] u32
  WS_PCNT  = 265472u,   // [par][4][64][32] u32
  WS_POBJ  = 331008u,   // [4][64] f
  WS_PMIN  = 332032u,   // [4][32][64] u64
  WS_GSUM  = 397568u,   // [par][4][2080] f
  WS_REP   = 464128u,   // [4][32][64] f
  WS_TCNT  = 496896u,   // [128] u32
  WS_PSUM  = 497408u    // [par][4][64][2080] f
};

__device__ __forceinline__ void tf2x32(u32 k0, u32 k1, u32 x0, u32 x1, u32& o0, u32& o1){
  u32 ks2 = k0 ^ k1 ^ 0x1BD11BDAu;
  x0 += k0; x1 += k1;
#define TFR(r) { x0 += x1; x1 = (x1<<(r))|(x1>>(32-(r))); x1 ^= x0; }
  TFR(13) TFR(15) TFR(26) TFR(6)
  x0 += k1;  x1 += ks2 + 1u;
  TFR(17) TFR(29) TFR(16) TFR(24)
  x0 += ks2; x1 += k0 + 2u;
  TFR(13) TFR(15) TFR(26) TFR(6)
  x0 += k0;  x1 += k1 + 3u;
  TFR(17) TFR(29) TFR(16) TFR(24)
  x0 += k1;  x1 += ks2 + 4u;
  TFR(13) TFR(15) TFR(26) TFR(6)
  x0 += ks2; x1 += k0 + 5u;
#undef TFR
  o0 = x0; o1 = x1;
}

__device__ __forceinline__ u32 fenc(float f){ u32 u=__float_as_uint(f); return (u&0x80000000u)? ~u : (u|0x80000000u); }
__device__ __forceinline__ float fdec(u32 u){ u32 v=(u&0x80000000u)? (u&0x7fffffffu) : ~u; return __uint_as_float(v); }

// ---------------- init kernel (unchanged from R1: PRNG + stable sorts + C0/XH + barrier zero) ----
__global__ __launch_bounds__(1024, 1) void kinit(const float* __restrict__ E, char* __restrict__ ws){
  const int tid = threadIdx.x;
  u32* bar   = (u32*)(ws + WS_BAR);
  u32* sel   = (u32*)(ws + WS_SEL);
  u32* keys1 = (u32*)(ws + WS_KEYS1);
  u32* keys2 = (u32*)(ws + WS_KEYS2);
  u32* a1k = (u32*)(ws + WS_A1K); u32* a1v = (u32*)(ws + WS_A1V);
  u32* a2k = (u32*)(ws + WS_A2K); u32* a2v = (u32*)(ws + WS_A2V);
  float* C0 = (float*)(ws + WS_C0);
  float* XH = (float*)(ws + WS_XHEAD);

  __shared__ u32 hist[8192];
  __shared__ u32 lsum[1024];
  __shared__ u32 sel_s[32];

  if (tid < 4) bar[tid] = 0u;

  u32 i0,i1; tf2x32(0u,42u, 0u,0u, i0,i1);
  u32 key10,key11, s10,s11;
  tf2x32(i0,i1, 0u,0u, key10,key11);
  tf2x32(i0,i1, 0u,1u, s10,s11);
  u32 s20,s21; tf2x32(key10,key11, 0u,1u, s20,s21);

  for (int i = tid; i < 8192; i += 1024){
    u32 y0,y1;
    tf2x32(s10,s11, 0u,(u32)i, y0,y1); keys1[i] = y0 ^ y1;
    tf2x32(s20,s21, 0u,(u32)i, y0,y1); keys2[i] = y0 ^ y1;
  }
  for (int i = tid; i < 8192; i += 1024){
    int b = i >> 11; int rem = i & 2047;
    XH[i] = E[(size_t)b*Nn*Dd + rem];
  }
  __syncthreads();

  for (int rnd = 0; rnd < 2; rnd++){
    u32* keys = rnd ? keys2 : keys1;
    u32* ak   = rnd ? a2k   : a1k;
    u32* av   = rnd ? a2v   : a1v;
    for (int i = tid; i < 8192; i += 1024) hist[i] = 0u;
    __syncthreads();
    for (int i = tid; i < 8192; i += 1024) atomicAdd(&hist[keys[i]>>19], 1u);
    __syncthreads();
    { u32 s = 0;
      for (int j = 0; j < 8; j++) s += hist[tid*8+j];
      lsum[tid] = s; }
    __syncthreads();
    for (int st = 1; st < 1024; st <<= 1){
      u32 v = (tid >= st) ? lsum[tid-st] : 0u;
      __syncthreads();
      lsum[tid] += v;
      __syncthreads();
    }
    { u32 run = tid ? lsum[tid-1] : 0u;
      for (int j = 0; j < 8; j++){ u32 c = hist[tid*8+j]; hist[tid*8+j] = run; run += c; } }
    __syncthreads();
    for (int i = tid; i < 8192; i += 1024){
      u32 kx = keys[i];
      u32 pos = atomicAdd(&hist[kx>>19], 1u);
      ak[pos] = kx; av[pos] = (u32)i;
    }
    __syncthreads();
    for (int bkt = tid; bkt < 8192; bkt += 1024){
      int s0 = bkt ? (int)hist[bkt-1] : 0;
      int e0 = (int)hist[bkt];
      for (int i = s0+1; i < e0; i++){
        u32 kx = ak[i], vx = av[i];
        int j = i-1;
        while (j >= s0 && (ak[j] > kx || (ak[j] == kx && av[j] > vx))){
          ak[j+1] = ak[j]; av[j+1] = av[j]; j--;
        }
        ak[j+1] = kx; av[j+1] = vx;
      }
    }
    __syncthreads();
  }
  if (tid < 32){ u32 p = a2v[tid]; u32 sj = a1v[p]; sel[tid] = sj; sel_s[tid] = sj; }
  __syncthreads();
  for (int i = tid; i < 8192; i += 1024){
    int b = i >> 11; int k = (i >> 6) & 31; int d = i & 63;
    C0[i] = E[(size_t)b*Nn*Dd + (size_t)sel_s[k]*Dd + d];
  }
}

__device__ __forceinline__ void grid_barrier(u32* bar){
  __syncthreads();
  if (threadIdx.x == 0){
    __threadfence();
    u32 g = __hip_atomic_load(&bar[1], __ATOMIC_RELAXED, __HIP_MEMORY_SCOPE_AGENT);
    u32 a = __hip_atomic_fetch_add(&bar[0], 1u, __ATOMIC_ACQ_REL, __HIP_MEMORY_SCOPE_AGENT);
    if (a == (u32)(NBLK-1)){
      __hip_atomic_store(&bar[0], 0u, __ATOMIC_RELAXED, __HIP_MEMORY_SCOPE_AGENT);
      __hip_atomic_fetch_add(&bar[1], 1u, __ATOMIC_RELEASE, __HIP_MEMORY_SCOPE_AGENT);
    } else {
      while (__hip_atomic_load(&bar[1], __ATOMIC_ACQUIRE, __HIP_MEMORY_SCOPE_AGENT) == g){
        __builtin_amdgcn_s_sleep(2);
      }
    }
    __threadfence();
  }
  __syncthreads();
}

#define CALC_XX() do { float s0=0.f,s1=0.f,s2=0.f,s3=0.f; \
  _Pragma("unroll") \
  for (int j=0;j<16;j++){ s0+=x[4*j]*x[4*j]; s1+=x[4*j+1]*x[4*j+1]; s2+=x[4*j+2]*x[4*j+2]; s3+=x[4*j+3]*x[4*j+3]; } \
  xx=(s0+s1)+(s2+s3); } while(0)

// 8 clusters per thread, k = kbase + j. Same per-k accumulation order as R1 (bit-identical dists).
#define CALC_DIST8() do { \
  _Pragma("unroll") \
  for (int j=0;j<8;j++){ \
    const int kq_ = kbase + j; \
    const float4* cp = (const float4*)&Cl[kq_*64]; \
    float s0=0.f,s1=0.f,s2=0.f,s3=0.f; \
    _Pragma("unroll") \
    for (int q=0;q<16;q++){ float4 c = cp[q]; s0+=x[4*q]*c.x; s1+=x[4*q+1]*c.y; s2+=x[4*q+2]*c.z; s3+=x[4*q+3]*c.w; } \
    float dot=(s0+s1)+(s2+s3); \
    dloc[j]=(ccl[kq_]+xx)-2.f*dot; \
  } } while(0)

__global__ __launch_bounds__(NTHR, 2) void kmain(const float* __restrict__ E, const float* __restrict__ LW,
                                                 float* __restrict__ out, char* __restrict__ ws){
  const int tid   = threadIdx.x;
  const int bid   = blockIdx.x;
  const int b     = bid >> 6;        // batch
  const int chunk = bid & 63;        // 64 chunks of 128 points
  const int kg    = tid >> 7;        // k-group 0..3 (wave-uniform: 2 waves per kg)
  const int p     = tid & 127;       // local point
  const int n     = (chunk << 7) + p;
  const int kbase = kg << 3;

  u32*   bar   = (u32*)(ws + WS_BAR);
  u32*   maskh = (u32*)(ws + WS_MASKH);
  float* C0    = (float*)(ws + WS_C0);
  float* XH    = (float*)(ws + WS_XHEAD);
  u32*   Pchg  = (u32*)(ws + WS_PCHG);
  u32*   Pcnt  = (u32*)(ws + WS_PCNT);
  float* Pobj  = (float*)(ws + WS_POBJ);
  u64*   Pmin  = (u64*)(ws + WS_PMIN);
  float* Gsum  = (float*)(ws + WS_GSUM);
  float* RepG  = (float*)(ws + WS_REP);
  u32*   Tcnt  = (u32*)(ws + WS_TCNT);
  float* Psum  = (float*)(ws + WS_PSUM);

  __shared__ float Cl[2048];
  __shared__ float ccl[32];
  __shared__ float part[2080];     // d-major: part[d*32+k]; W at 2048+k
  __shared__ u32   mindl[128];
  __shared__ u32   msk32[128];
  __shared__ u32   cntl[32];
  __shared__ u32   cntall[128];
  __shared__ float newX[2048];
  __shared__ float red[512];
  __shared__ u64   kminl[32];
  __shared__ u64   gminl[32];

  // full point in regs (compile-time indexed only)
  float x[64]; float xx;
  { const float4* xr = (const float4*)(E + (size_t)(b*Nn + n)*Dd);
    #pragma unroll
    for (int j=0;j<16;j++){ float4 v = xr[j]; x[4*j]=v.x; x[4*j+1]=v.y; x[4*j+2]=v.z; x[4*j+3]=v.w; } }
  CALC_XX();
  const float w = expf(LW[b*Nn + n]);
  // 16-d scatter slice (loaded separately to keep reg indices compile-time)
  float wxs[16];
  { const float4* sr = (const float4*)(E + (size_t)(b*Nn + n)*Dd + (kg<<4));
    #pragma unroll
    for (int j=0;j<4;j++){ float4 v = sr[j]; wxs[4*j]=w*v.x; wxs[4*j+1]=w*v.y; wxs[4*j+2]=w*v.z; wxs[4*j+3]=w*v.w; } }

  u32 kl0, kl1; tf2x32(0u,42u, 0u,1u, kl0, kl1);

  for (int i = tid; i < 2048; i += NTHR) Cl[i] = C0[b*2048 + i];
  __syncthreads();
  if (tid < 32){ float s=0.f; const float* cr=&Cl[tid*64];
    #pragma unroll
    for (int d2=0; d2<64; d2++) s += cr[d2]*cr[d2];
    ccl[tid]=s; }
  __syncthreads();

  u32 prev8 = 0u;
  float dloc[8];

  for (int t = 0; t < MAXIT; t++){
    const int par = t & 1;
    // ---------- phase 1 ----------
    for (int i = tid; i < 2080; i += NTHR) part[i] = 0.f;
    if (tid < 128){ mindl[tid] = 0xFFFFFFFFu; msk32[tid] = 0u; }
    if (tid < 32) cntl[tid] = 0u;
    __syncthreads();

    CALC_DIST8();
    { float m8 = dloc[0];
      #pragma unroll
      for (int j=1;j<8;j++) m8 = fminf(m8, dloc[j]);
      atomicMin(&mindl[p], fenc(m8)); }
    __syncthreads();
    const float mind = fdec(mindl[p]);
    u32 mask8 = 0u;
    #pragma unroll
    for (int j=0;j<8;j++) if (fabsf(dloc[j]-mind) < 1e-8f) mask8 |= (1u<<j);
    int changed = (t==0) ? 1 : (mask8 != prev8);
    prev8 = mask8;
    atomicOr(&msk32[p], mask8 << (kg*8));
    int nchg = __syncthreads_count(changed);

    if (chunk == 0 && tid < 32) maskh[par*128 + b*32 + tid] = msk32[tid];
    { u32 mm = msk32[p];
      while (mm){
        int k = __ffs(mm) - 1; mm &= mm - 1;
        #pragma unroll
        for (int q=0;q<16;q++) atomicAdd(&part[((kg<<4)+q)*32 + k], wxs[q]);
      }
      if (kg == 0){
        u32 m2 = msk32[p];
        while (m2){ int k = __ffs(m2) - 1; m2 &= m2 - 1; atomicAdd(&cntl[k],1u); atomicAdd(&part[2048+k], w); }
      } }
    __syncthreads();
    { float* dst = Psum + (size_t)(((par*4)+b)*64 + chunk) * 2080;
      for (int i = tid; i < 2080; i += NTHR) dst[i] = part[i];
      if (tid < 32) Pcnt[(((par*4)+b)*64 + chunk)*32 + tid] = cntl[tid];
      if (tid == 0) Pchg[par*256 + bid] = (u32)nchg; }
    grid_barrier(bar);

    // ---------- stage A: convergence + counts + distributed reduce ----------
    int anych;
    { u32 v = 0; if (tid < 256) v = Pchg[par*256 + tid];
      anych = __syncthreads_count(v != 0u); }
    if (anych == 0) break;

    u32 cml = 1u;
    if (tid < 128){ int bb = tid >> 5, kq = tid & 31;
      u32 s = 0;
      for (int c = 0; c < 64; c++) s += Pcnt[(((par*4)+bb)*64 + c)*32 + kq];
      cntall[tid] = s; cml = s; }
    int nempty = __syncthreads_count(tid < 128 && cml == 0u);

    if (tid < 33){
      int e = chunk*33 + tid;
      if (e < 2080){
        const float* src = Psum + (size_t)(((par*4)+b)*64) * 2080 + e;
        float s = 0.f;
        for (int c = 0; c < 64; c++) s += src[(size_t)c*2080];
        Gsum[((par*4)+b)*2080 + e] = s;
      } }
    grid_barrier(bar);

    // ---------- stage B: broadcast + (rare) empty fixup + C update ----------
    for (int i = tid; i < 2080; i += NTHR) part[i] = Gsum[((par*4)+b)*2080 + i];
    __syncthreads();

    if (nempty){
      u32 g0, g1; tf2x32(kl0, kl1, 0u, (u32)t, g0, g1);
      for (int k = 0; k < 32; k++){
        if (cntall[b*32 + k] != 0u) continue;
        int jj = b*32 + k;
        u32 y0, y1; tf2x32(g0, g1, 0u, (u32)jj, y0, y1);
        u32 ridx = (y0 ^ y1) & 8191u;
        u32 mj = maskh[par*128 + b*32 + k];
        float wj = expf(LW[b*Nn + k]);
        if (tid < 64){
          float xo = XH[(b*32 + k)*64 + tid];
          float xn = (ridx < 32u) ? XH[(b*32 + (int)ridx)*64 + tid]
                                  : E[(size_t)(b*Nn + (int)ridx)*Dd + tid];
          newX[k*64 + tid] = xn;
          float dxw = wj * (xn - xo);
          u32 m2 = mj;
          while (m2){ int kq = __ffs(m2) - 1; m2 &= m2 - 1; part[tid*32 + kq] += dxw; }
        }
      }
      __syncthreads();
      grid_barrier(bar);
      if (chunk == 0){
        for (int k = 0; k < 32; k++){
          if (cntall[b*32 + k] != 0u) continue;
          if (tid < 64) XH[(b*32 + k)*64 + tid] = newX[k*64 + tid];
        }
        __syncthreads();
        if (p < 32 && cntall[b*32 + p] == 0u){
          #pragma unroll
          for (int d2 = 0; d2 < 64; d2++) x[d2] = newX[p*64 + d2];
          CALC_XX();
          #pragma unroll
          for (int q = 0; q < 16; q++) wxs[q] = w * newX[p*64 + (kg<<4) + q];
        }
      }
      __syncthreads();
    }

    for (int i = tid; i < 2048; i += NTHR){
      int k = i >> 6, d = i & 63;
      Cl[i] = part[d*32 + k] / fmaxf(part[2048 + k], 1e-12f);
    }
    __syncthreads();
    if (tid < 32){ float s=0.f; const float* cr=&Cl[tid*64];
      #pragma unroll
      for (int d2=0; d2<64; d2++) s += cr[d2]*cr[d2];
      ccl[tid]=s; }
    __syncthreads();
  }

  // ---------- finalize 1: final dists (regs), ass out, per-block mins/obj, zero Rep ----------
  if (tid < 128) mindl[tid] = 0xFFFFFFFFu;
  if (tid < 32) kminl[tid] = ~0ull;
  __syncthreads();
  CALC_DIST8();
  { float m8 = dloc[0];
    #pragma unroll
    for (int j=1;j<8;j++) m8 = fminf(m8, dloc[j]);
    atomicMin(&mindl[p], fenc(m8)); }
  __syncthreads();
  const float mind = fdec(mindl[p]);

  { float4 v0, v1;
    v0.x = (prev8     &1u)?1.f:0.f; v0.y=((prev8>>1)&1u)?1.f:0.f; v0.z=((prev8>>2)&1u)?1.f:0.f; v0.w=((prev8>>3)&1u)?1.f:0.f;
    v1.x = ((prev8>>4)&1u)?1.f:0.f; v1.y=((prev8>>5)&1u)?1.f:0.f; v1.z=((prev8>>6)&1u)?1.f:0.f; v1.w=((prev8>>7)&1u)?1.f:0.f;
    float4* ap = (float4*)(out + (size_t)(b*Nn + n)*32 + kbase);
    ap[0] = v0; ap[1] = v1; }

  #pragma unroll
  for (int j=0;j<8;j++){
    u64 pk = ((u64)fenc(dloc[j]) << 32) | (u32)n;
    atomicMin(&kminl[kbase + j], pk);
  }
  red[tid] = (kg == 0) ? mind : 0.f;
  __syncthreads();
  for (int s2 = 256; s2 > 0; s2 >>= 1){
    if (tid < s2) red[tid] += red[tid + s2];
    __syncthreads();
  }
  if (tid == 0) Pobj[b*64 + chunk] = red[0];
  if (tid < 32) Pmin[(size_t)(b*32 + tid)*64 + chunk] = kminl[tid];
  if (tid < 32) RepG[bid*32 + tid] = 0.f;
  if (bid < 128 && tid == 0) Tcnt[bid] = 0u;
  grid_barrier(bar);

  // ---------- finalize 1b: global mins; tie accumulation from registers ----------
  if (tid < 32){
    u64 m = ~0ull;
    for (int c = 0; c < 64; c++){ u64 v = Pmin[(size_t)(b*32 + tid)*64 + c]; if (v < m) m = v; }
    gminl[tid] = m;
  }
  __syncthreads();
  #pragma unroll
  for (int j=0;j<8;j++){
    int k = kbase + j;
    u64 gm = gminl[k];
    float gmd = fdec((u32)(gm >> 32));
    if (fabsf(dloc[j] - gmd) < 1e-8f){
      atomicAdd(&Tcnt[b*32 + k], 1u);
      #pragma unroll
      for (int d2 = 0; d2 < 64; d2++) atomicAdd(&RepG[(b*32 + k)*64 + d2], x[d2]);
    }
  }
  grid_barrier(bar);

  // ---------- finalize 2 ----------
  {
    const size_t OFF_C    = (size_t)Bb*Nn*Kk;
    const size_t OFF_REP  = OFF_C + (size_t)Bb*Kk*Dd;
    const size_t OFF_RIDX = OFF_REP + (size_t)Bb*Kk*Dd;
    const size_t OFF_OBJ  = OFF_RIDX + (size_t)Bb*Kk;
    if ((bid & 63) < 32){
      const int k2 = bid & 31;
      float cnt = (float)Tcnt[b*32 + k2];
      if (tid < 64){
        out[OFF_C   + (size_t)(b*32 + k2)*64 + tid] = Cl[k2*64 + tid];
        out[OFF_REP + (size_t)(b*32 + k2)*64 + tid] = RepG[(b*32 + k2)*64 + tid] / cnt;
      }
      if (tid == 0) out[OFF_RIDX + b*32 + k2] = (float)(u32)(gminl[k2] & 0xffffffffu);
    }
    if ((bid & 63) == 32){
      red[tid] = (tid < 64) ? Pobj[b*64 + tid] : 0.f;
      __syncthreads();
      if (tid == 0){ float s = 0.f;
        for (int i2 = 0; i2 < 64; i2++) s += red[i2];
        out[OFF_OBJ + b] = s / (float)Nn; }
    }
  }
}

extern "C" void kernel_launch(void* const* d_in, const int* in_sizes, int n_in,
                              void* d_out, int out_size, void* d_ws, size_t ws_size,
                              hipStream_t stream) {
  const float* E  = (const float*)d_in[0];
  const float* LW = (const float*)d_in[1];
  float* out = (float*)d_out;
  char*  ws  = (char*)d_ws;
  (void)in_sizes; (void)n_in; (void)out_size; (void)ws_size;
  kinit<<<dim3(1),    dim3(1024), 0, stream>>>(E, ws);
  kmain<<<dim3(NBLK), dim3(NTHR), 0, stream>>>(E, LW, out, ws);
}

// Round 4
// 2876.740 us; speedup vs baseline: 1.0876x; 1.0876x over previous
//
#include <hip/hip_runtime.h>
#include <stdint.h>
#include <math.h>

typedef unsigned int u32;
typedef unsigned long long u64;

#define Bb 4
#define Nn 8192
#define Dd 64
#define Kk 32
#define MAXIT 30
#define NCH   64     // chunks per batch
#define K1THR 128    // 1 point per thread, 256 blocks total

// ---- workspace layout (bytes); total 6,621,760 ----
enum : u32 {
  WS_CONV = 0u,        // u32 convergence flag (zeroed by kinit)
  WS_CCL  = 64u,       // [4][32] f  cluster sq-norms
  WS_CW   = 576u,      // [4][32][64] f current centroids
  WS_XH   = 33344u,    // [4][32][64] f mutable first-32 rows of X
  WS_MSK  = 66112u,    // [4][8192] u32 last assignment masks (zeroed by kinit)
  WS_PCHG = 197184u,   // [256] u32
  WS_PCNT = 198208u,   // [4][64][32] u32
  WS_POBJ = 230976u,   // [4][64] f
  WS_PMIN = 232000u,   // [4][32][64] u64 (8-aligned)
  WS_PSUM = 297536u,   // [4][64][2080] f   (also aliased as sort scratch in kinit)
  WS_DM   = 2427456u   // [4][32][8192] f final distances
};
// kinit-only aliases inside WS_PSUM region (dead after kinit):
enum : u32 {
  SS_K1 = WS_PSUM +      0u,
  SS_K2 = WS_PSUM +  32768u,
  SS_AK1= WS_PSUM +  65536u,
  SS_AV1= WS_PSUM +  98304u,
  SS_AK2= WS_PSUM + 131072u,
  SS_AV2= WS_PSUM + 163840u
};

// Threefry-2x32, 20 rounds — jax threefry_partitionable semantics
__device__ __forceinline__ void tf2x32(u32 k0, u32 k1, u32 x0, u32 x1, u32& o0, u32& o1){
  u32 ks2 = k0 ^ k1 ^ 0x1BD11BDAu;
  x0 += k0; x1 += k1;
#define TFR(r) { x0 += x1; x1 = (x1<<(r))|(x1>>(32-(r))); x1 ^= x0; }
  TFR(13) TFR(15) TFR(26) TFR(6)
  x0 += k1;  x1 += ks2 + 1u;
  TFR(17) TFR(29) TFR(16) TFR(24)
  x0 += ks2; x1 += k0 + 2u;
  TFR(13) TFR(15) TFR(26) TFR(6)
  x0 += k0;  x1 += k1 + 3u;
  TFR(17) TFR(29) TFR(16) TFR(24)
  x0 += k1;  x1 += ks2 + 4u;
  TFR(13) TFR(15) TFR(26) TFR(6)
  x0 += ks2; x1 += k0 + 5u;
#undef TFR
  o0 = x0; o1 = x1;
}

__device__ __forceinline__ u32 fenc(float f){ u32 u=__float_as_uint(f); return (u&0x80000000u)? ~u : (u|0x80000000u); }
__device__ __forceinline__ float fdec(u32 u){ u32 v=(u&0x80000000u)? (u&0x7fffffffu) : ~u; return __uint_as_float(v); }

// ---------------- init: PRNG + 2 stable sorts + Cw/ccl/XH/Msk/conv init ----------------
__global__ __launch_bounds__(1024, 1) void kinit(const float* __restrict__ E, char* __restrict__ ws){
  const int tid = threadIdx.x;
  u32* conv  = (u32*)(ws + WS_CONV);
  u32* Msk   = (u32*)(ws + WS_MSK);
  u32* keys1 = (u32*)(ws + SS_K1);
  u32* keys2 = (u32*)(ws + SS_K2);
  u32* a1k = (u32*)(ws + SS_AK1); u32* a1v = (u32*)(ws + SS_AV1);
  u32* a2k = (u32*)(ws + SS_AK2); u32* a2v = (u32*)(ws + SS_AV2);
  float* Cw = (float*)(ws + WS_CW);
  float* XH = (float*)(ws + WS_XH);
  float* cclw = (float*)(ws + WS_CCL);

  __shared__ u32 hist[8192];
  __shared__ u32 lsum[1024];
  __shared__ u32 sel_s[32];

  if (tid == 0) conv[0] = 0u;
  for (int i = tid; i < Bb*Nn; i += 1024) Msk[i] = 0u;

  // key chain: root=(0,42); k_init = enc(0,0); sub1 = enc_kinit(0,1); key1 = enc_kinit(0,0); sub2 = enc_key1(0,1)
  u32 i0,i1; tf2x32(0u,42u, 0u,0u, i0,i1);
  u32 key10,key11, s10,s11;
  tf2x32(i0,i1, 0u,0u, key10,key11);
  tf2x32(i0,i1, 0u,1u, s10,s11);
  u32 s20,s21; tf2x32(key10,key11, 0u,1u, s20,s21);

  for (int i = tid; i < 8192; i += 1024){
    u32 y0,y1;
    tf2x32(s10,s11, 0u,(u32)i, y0,y1); keys1[i] = y0 ^ y1;
    tf2x32(s20,s21, 0u,(u32)i, y0,y1); keys2[i] = y0 ^ y1;
  }
  for (int i = tid; i < 8192; i += 1024){
    int b = i >> 11; int rem = i & 2047;
    XH[i] = E[(size_t)b*Nn*Dd + rem];
  }
  __syncthreads();

  for (int rnd = 0; rnd < 2; rnd++){
    u32* keys = rnd ? keys2 : keys1;
    u32* ak   = rnd ? a2k   : a1k;
    u32* av   = rnd ? a2v   : a1v;
    for (int i = tid; i < 8192; i += 1024) hist[i] = 0u;
    __syncthreads();
    for (int i = tid; i < 8192; i += 1024) atomicAdd(&hist[keys[i]>>19], 1u);
    __syncthreads();
    { u32 s = 0;
      for (int j = 0; j < 8; j++) s += hist[tid*8+j];
      lsum[tid] = s; }
    __syncthreads();
    for (int st = 1; st < 1024; st <<= 1){
      u32 v = (tid >= st) ? lsum[tid-st] : 0u;
      __syncthreads();
      lsum[tid] += v;
      __syncthreads();
    }
    { u32 run = tid ? lsum[tid-1] : 0u;
      for (int j = 0; j < 8; j++){ u32 c = hist[tid*8+j]; hist[tid*8+j] = run; run += c; } }
    __syncthreads();
    for (int i = tid; i < 8192; i += 1024){
      u32 kx = keys[i];
      u32 pos = atomicAdd(&hist[kx>>19], 1u);
      ak[pos] = kx; av[pos] = (u32)i;
    }
    __syncthreads();
    for (int bkt = tid; bkt < 8192; bkt += 1024){
      int s0 = bkt ? (int)hist[bkt-1] : 0;
      int e0 = (int)hist[bkt];
      for (int i = s0+1; i < e0; i++){
        u32 kx = ak[i], vx = av[i];
        int j = i-1;
        while (j >= s0 && (ak[j] > kx || (ak[j] == kx && av[j] > vx))){
          ak[j+1] = ak[j]; av[j+1] = av[j]; j--;
        }
        ak[j+1] = kx; av[j+1] = vx;
      }
    }
    __syncthreads();
  }
  if (tid < 32){ u32 p = a2v[tid]; sel_s[tid] = a1v[p]; }
  __syncthreads();
  // Cw[b][k][d] = E[b][sel[k]][d]
  for (int i = tid; i < Bb*Kk*Dd; i += 1024){
    int b = i >> 11; int k = (i >> 6) & 31; int d = i & 63;
    Cw[i] = E[(size_t)b*Nn*Dd + (size_t)sel_s[k]*Dd + d];
  }
  __syncthreads();   // FIX (R3 bug): Cw fully written before cclw reads it
  // ccl[b][k] = sum_d c^2 (d ascending — keep this exact order everywhere)
  if (tid < 128){
    int b = tid >> 5, k = tid & 31;
    const float* cr = &Cw[0] + (b*32 + k)*64;
    float s = 0.f;
    for (int d = 0; d < 64; d++) s += cr[d]*cr[d];
    cclw[tid] = s;
  }
}

#define CALC_XX() do { float s0=0.f,s1=0.f,s2=0.f,s3=0.f; \
  _Pragma("unroll") \
  for (int j=0;j<16;j++){ s0+=x[4*j]*x[4*j]; s1+=x[4*j+1]*x[4*j+1]; s2+=x[4*j+2]*x[4*j+2]; s3+=x[4*j+3]*x[4*j+3]; } \
  xx=(s0+s1)+(s2+s3); } while(0)

#define CALC_DIST32() do { \
  _Pragma("unroll") \
  for (int k=0;k<32;k++){ \
    const float4* cp = (const float4*)&Cl[k*64]; \
    float s0=0.f,s1=0.f,s2=0.f,s3=0.f; \
    _Pragma("unroll") \
    for (int q=0;q<16;q++){ float4 c = cp[q]; s0+=x[4*q]*c.x; s1+=x[4*q+1]*c.y; s2+=x[4*q+2]*c.z; s3+=x[4*q+3]*c.w; } \
    float dot=(s0+s1)+(s2+s3); \
    dloc[k]=(ccl[k]+xx)-2.f*dot; \
  } } while(0)

#define LOAD_POINT() do { \
  const float* xsrc = (n < 32) ? (XH + (size_t)(b*32 + n)*64) : (E + (size_t)(b*Nn + n)*Dd); \
  const float4* xr = (const float4*)xsrc; \
  _Pragma("unroll") \
  for (int j=0;j<16;j++){ float4 v = xr[j]; x[4*j]=v.x; x[4*j+1]=v.y; x[4*j+2]=v.z; x[4*j+3]=v.w; } } while(0)

// ---------------- K1: assignment + per-chunk partial sums (256 blocks x 128 thr) ----------------
__global__ __launch_bounds__(K1THR) void k_assign(const float* __restrict__ E, const float* __restrict__ LW,
                                                  char* __restrict__ ws){
  const u32* conv = (const u32*)(ws + WS_CONV);
  if (conv[0]) return;
  const int tid = threadIdx.x;
  const int bid = blockIdx.x;
  const int b   = bid >> 6;
  const int c   = bid & 63;
  const int n   = (c << 7) + tid;

  const float* Cw   = (const float*)(ws + WS_CW);
  const float* cclw = (const float*)(ws + WS_CCL);
  const float* XH   = (const float*)(ws + WS_XH);
  u32*   Msk  = (u32*)(ws + WS_MSK);
  u32*   Pchg = (u32*)(ws + WS_PCHG);
  u32*   Pcnt = (u32*)(ws + WS_PCNT);
  float* Psum = (float*)(ws + WS_PSUM);

  __shared__ float Cl[2048];
  __shared__ float ccl[32];
  __shared__ float part[2080];   // d-major: part[d*32+k]; W at 2048+k
  __shared__ u32   cntl[32];

  { float4* c4 = (float4*)Cl; const float4* g4 = (const float4*)(Cw + b*2048);
    for (int i = tid; i < 512; i += K1THR) c4[i] = g4[i]; }
  if (tid < 32) ccl[tid] = cclw[b*32 + tid];
  for (int i = tid; i < 2080; i += K1THR) part[i] = 0.f;
  if (tid < 32) cntl[tid] = 0u;

  float x[64]; float xx;
  LOAD_POINT();
  CALC_XX();
  const float w = expf(LW[b*Nn + n]);
  __syncthreads();

  float dloc[32];
  CALC_DIST32();
  float mind = dloc[0];
  #pragma unroll
  for (int k=1;k<32;k++) mind = fminf(mind, dloc[k]);
  u32 mask = 0u;
  #pragma unroll
  for (int k=0;k<32;k++) if (fabsf(dloc[k]-mind) < 1e-8f) mask |= (1u<<k);
  int changed = (mask != Msk[b*Nn + n]);
  Msk[b*Nn + n] = mask;

  { u32 mm = mask;
    while (mm){
      int k = __ffs(mm) - 1; mm &= mm - 1;
      #pragma unroll
      for (int d2=0; d2<64; d2++) atomicAdd(&part[d2*32 + k], w*x[d2]);
      atomicAdd(&part[2048 + k], w);
      atomicAdd(&cntl[k], 1u);
    } }
  int nchg = __syncthreads_count(changed);

  { float* dst = Psum + (size_t)(b*64 + c)*2080;
    for (int e = tid; e < 2080; e += K1THR) dst[e] = part[e];
    if (tid < 32) Pcnt[(b*64 + c)*32 + tid] = cntl[tid];
    if (tid == 0) Pchg[bid] = (u32)nchg; }
}

// ---------------- K2: reduce + convergence + empty fixup + C update (4 blocks x 1024 thr) ----------------
__global__ __launch_bounds__(1024, 1) void k_update(const float* __restrict__ E, const float* __restrict__ LW,
                                                    char* __restrict__ ws, int t){
  u32* conv = (u32*)(ws + WS_CONV);
  if (conv[0]) return;
  const int tid = threadIdx.x;
  const int b   = blockIdx.x;

  const u32*  Msk  = (const u32*)(ws + WS_MSK);
  u32*   Pchg = (u32*)(ws + WS_PCHG);
  u32*   Pcnt = (u32*)(ws + WS_PCNT);
  float* Psum = (float*)(ws + WS_PSUM);
  float* Cw   = (float*)(ws + WS_CW);
  float* XH   = (float*)(ws + WS_XH);
  float* cclw = (float*)(ws + WS_CCL);

  __shared__ float part[2080];
  __shared__ float buf[2048];       // fixup staging, then new C
  __shared__ u32   cnt[32];

  // convergence across ALL batches
  u32 v = (tid < 256) ? Pchg[tid] : 0u;
  int anych = __syncthreads_count(v != 0u);
  if (anych == 0){
    if (b == 0 && tid == 0) conv[0] = 1u;   // freeze: skip update forever
    return;
  }

  // reduce partial sums (chunk ascending — deterministic)
  {
    const float* src = Psum + (size_t)(b*64)*2080;
    for (int e = tid; e < 2080; e += 1024){
      float s = 0.f;
      for (int c = 0; c < 64; c++) s += src[(size_t)c*2080 + e];
      part[e] = s;
    }
  }
  u32 myc = 1u;
  if (tid < 32){
    u32 s = 0;
    for (int c = 0; c < 64; c++) s += Pcnt[(b*64 + c)*32 + tid];
    cnt[tid] = s; myc = s;
  }
  int nempty = __syncthreads_count(tid < 32 && myc == 0u);

  if (nempty){
    // k_loop = enc_(0,42)(0,1);  g = fold_in(k_loop, t)
    u32 kl0, kl1; tf2x32(0u,42u, 0u,1u, kl0, kl1);
    u32 g0, g1;  tf2x32(kl0, kl1, 0u, (u32)t, g0, g1);
    // phase 1: gather all replacement rows (pre-replacement X) + adjust sums
    for (int k = 0; k < 32; k++){
      if (cnt[k] != 0u) continue;
      int j = b*32 + k;
      u32 y0, y1; tf2x32(g0, g1, 0u, (u32)j, y0, y1);
      u32 ridx = (y0 ^ y1) & 8191u;
      u32 mj = Msk[b*Nn + k];          // head point k's current mask
      float wj = expf(LW[b*Nn + k]);
      if (tid < 64){
        float xo = XH[(b*32 + k)*64 + tid];
        float xn = (ridx < 32u) ? XH[(b*32 + (int)ridx)*64 + tid]
                                : E[(size_t)(b*Nn + (int)ridx)*Dd + tid];
        buf[k*64 + tid] = xn;
        float dxw = wj * (xn - xo);
        u32 m2 = mj;
        while (m2){ int kq = __ffs(m2) - 1; m2 &= m2 - 1; part[tid*32 + kq] += dxw; }
      }
      __syncthreads();
    }
    // phase 2: commit X head rows
    for (int k = 0; k < 32; k++){
      if (cnt[k] != 0u) continue;
      if (tid < 64) XH[(b*32 + k)*64 + tid] = buf[k*64 + tid];
    }
    __syncthreads();
  }

  // C_new = sums / clip(W, 1e-12)
  for (int i = tid; i < 2048; i += 1024){
    int k = i >> 6, d = i & 63;
    buf[i] = part[d*32 + k] / fmaxf(part[2048 + k], 1e-12f);
  }
  __syncthreads();
  for (int i = tid; i < 2048; i += 1024) Cw[b*2048 + i] = buf[i];
  if (tid < 32){
    float s = 0.f; const float* cr = &buf[tid*64];
    for (int d = 0; d < 64; d++) s += cr[d]*cr[d];
    cclw[b*32 + tid] = s;
  }
}

// ---------------- KF1: final dists, ass out, per-chunk mins/obj (256 blocks x 128 thr) ----------------
__global__ __launch_bounds__(K1THR) void k_fin1(const float* __restrict__ E,
                                                float* __restrict__ out, char* __restrict__ ws){
  const int tid = threadIdx.x;
  const int bid = blockIdx.x;
  const int b   = bid >> 6;
  const int c   = bid & 63;
  const int n   = (c << 7) + tid;

  const float* Cw   = (const float*)(ws + WS_CW);
  const float* cclw = (const float*)(ws + WS_CCL);
  const float* XH   = (const float*)(ws + WS_XH);
  const u32*   Msk  = (const u32*)(ws + WS_MSK);
  float* Pobj = (float*)(ws + WS_POBJ);
  u64*   Pmin = (u64*)(ws + WS_PMIN);
  float* Dm   = (float*)(ws + WS_DM);

  __shared__ float Cl[2048];
  __shared__ float ccl[32];
  __shared__ u64   kminl[32];
  __shared__ float red[K1THR];

  { float4* c4 = (float4*)Cl; const float4* g4 = (const float4*)(Cw + b*2048);
    for (int i = tid; i < 512; i += K1THR) c4[i] = g4[i]; }
  if (tid < 32){ ccl[tid] = cclw[b*32 + tid]; kminl[tid] = ~0ull; }

  float x[64]; float xx;
  LOAD_POINT();
  CALC_XX();
  __syncthreads();

  float dloc[32];
  CALC_DIST32();
  float mind = dloc[0];
  #pragma unroll
  for (int k=1;k<32;k++) mind = fminf(mind, dloc[k]);

  // ass output = frozen last assignment
  { u32 msk = Msk[b*Nn + n];
    float4* dst = (float4*)(out + (size_t)(b*Nn + n)*32);
    #pragma unroll
    for (int q=0;q<8;q++){
      float4 vv;
      vv.x = ((msk>>(4*q  ))&1u) ? 1.f : 0.f;
      vv.y = ((msk>>(4*q+1))&1u) ? 1.f : 0.f;
      vv.z = ((msk>>(4*q+2))&1u) ? 1.f : 0.f;
      vv.w = ((msk>>(4*q+3))&1u) ? 1.f : 0.f;
      dst[q] = vv;
    } }

  #pragma unroll
  for (int k=0;k<32;k++){
    Dm[(size_t)(b*32 + k)*Nn + n] = dloc[k];
    u64 pk = ((u64)fenc(dloc[k]) << 32) | (u32)n;
    atomicMin(&kminl[k], pk);
  }
  red[tid] = mind;
  __syncthreads();
  for (int s2 = 64; s2 > 0; s2 >>= 1){
    if (tid < s2) red[tid] += red[tid + s2];
    __syncthreads();
  }
  if (tid < 32) Pmin[(size_t)(b*32 + tid)*64 + c] = kminl[tid];
  if (tid == 0) Pobj[b*64 + c] = red[0];
}

// ---------------- KF2: rep/rep_idx/C/obj (128 blocks x 256 thr) ----------------
__global__ __launch_bounds__(256) void k_fin2(const float* __restrict__ E,
                                              float* __restrict__ out, char* __restrict__ ws){
  const int tid = threadIdx.x;
  const int bid = blockIdx.x;
  const int b   = bid >> 5;
  const int k   = bid & 31;

  const float* Cw  = (const float*)(ws + WS_CW);
  const float* XH  = (const float*)(ws + WS_XH);
  const float* Pobj= (const float*)(ws + WS_POBJ);
  const u64*   Pmin= (const u64*)(ws + WS_PMIN);
  const float* Dm  = (const float*)(ws + WS_DM);

  __shared__ float acc[64];
  __shared__ float red[64];
  __shared__ u32   sh_cnt, sh_idx;
  __shared__ float sh_mind;

  if (tid == 0){
    u64 m = ~0ull;
    for (int c = 0; c < 64; c++){ u64 vv = Pmin[(size_t)(b*32 + k)*64 + c]; if (vv < m) m = vv; }
    sh_mind = fdec((u32)(m >> 32));
    sh_idx  = (u32)(m & 0xffffffffu);
    sh_cnt  = 0u;
  }
  if (tid < 64) acc[tid] = 0.f;
  __syncthreads();
  const float gmd = sh_mind;
  for (int nn = tid; nn < Nn; nn += 256){
    float dv = Dm[(size_t)(b*32 + k)*Nn + nn];
    if (fabsf(dv - gmd) < 1e-8f){
      atomicAdd(&sh_cnt, 1u);
      const float* xr = (nn < 32) ? (XH + (size_t)(b*32 + nn)*64) : (E + (size_t)(b*Nn + nn)*Dd);
      for (int d = 0; d < 64; d++) atomicAdd(&acc[d], xr[d]);
    }
  }
  __syncthreads();

  const size_t OFF_C    = (size_t)Bb*Nn*Kk;
  const size_t OFF_REP  = OFF_C + (size_t)Bb*Kk*Dd;
  const size_t OFF_RIDX = OFF_REP + (size_t)Bb*Kk*Dd;
  const size_t OFF_OBJ  = OFF_RIDX + (size_t)Bb*Kk;
  if (tid < 64){
    out[OFF_C   + (size_t)(b*32 + k)*64 + tid] = Cw[(b*32 + k)*64 + tid];
    out[OFF_REP + (size_t)(b*32 + k)*64 + tid] = acc[tid] / (float)sh_cnt;
  }
  if (tid == 0) out[OFF_RIDX + b*32 + k] = (float)sh_idx;
  if (k == 0){
    if (tid < 64) red[tid] = Pobj[b*64 + tid];
    __syncthreads();
    if (tid == 0){
      float s = 0.f;
      for (int i = 0; i < 64; i++) s += red[i];
      out[OFF_OBJ + b] = s / (float)Nn;
    }
  }
}

extern "C" void kernel_launch(void* const* d_in, const int* in_sizes, int n_in,
                              void* d_out, int out_size, void* d_ws, size_t ws_size,
                              hipStream_t stream) {
  const float* E  = (const float*)d_in[0];
  const float* LW = (const float*)d_in[1];
  float* out = (float*)d_out;
  char*  ws  = (char*)d_ws;
  (void)in_sizes; (void)n_in; (void)out_size; (void)ws_size;

  kinit<<<dim3(1), dim3(1024), 0, stream>>>(E, ws);
  for (int t = 0; t < MAXIT; t++){
    k_assign<<<dim3(256), dim3(K1THR), 0, stream>>>(E, LW, ws);
    k_update<<<dim3(4),   dim3(1024), 0, stream>>>(E, LW, ws, t);
  }
  k_fin1<<<dim3(256), dim3(K1THR), 0, stream>>>(E, out, ws);
  k_fin2<<<dim3(128), dim3(256),  0, stream>>>(E, out, ws);
}